// Round 9
// baseline (748.393 us; speedup 1.0000x reference)
//
#include <hip/hip_runtime.h>
#include <math.h>

#define N_NODES 50000
#define E_EDGES 800000
#define ET (E_EDGES + N_NODES)   // edges + self loops
#define L_LAYERS 4
#define NB_SCAN ((N_NODES + 255) / 256)   // 196

typedef __attribute__((ext_vector_type(8))) short short8;
typedef __attribute__((ext_vector_type(4))) float f32x4;

__device__ __forceinline__ float gelu_f(float x) {
    return 0.5f * x * (1.0f + erff(x * 0.70710678118654752f));
}

__device__ __forceinline__ void split_hl(float x, unsigned short& h, unsigned short& lo) {
    unsigned u = __float_as_uint(x);
    h = (unsigned short)(u >> 16);
    float hif = __uint_as_float(u & 0xffff0000u);
    lo = (unsigned short)(__float_as_uint(x - hif) >> 16);
}

// ---------------- graph preprocessing ----------------

__global__ __launch_bounds__(256) void count_pos(const int* __restrict__ ecol,
                                                 int* __restrict__ cnt,
                                                 int* __restrict__ aux) {
    int e = blockIdx.x * 256 + threadIdx.x;
    if (e >= ET) return;
    int c = (e < E_EDGES) ? ecol[e] : (e - E_EDGES);
    aux[e] = atomicAdd(&cnt[c], 1);
}

__global__ __launch_bounds__(256) void scan_part1(const int* __restrict__ cnt,
                                                  int* __restrict__ bsum) {
    __shared__ int red[256];
    int t = threadIdx.x;
    int i = blockIdx.x * 256 + t;
    red[t] = (i < N_NODES) ? cnt[i] : 0;
    __syncthreads();
#pragma unroll
    for (int off = 128; off; off >>= 1) {
        if (t < off) red[t] += red[t + off];
        __syncthreads();
    }
    if (t == 0) bsum[blockIdx.x] = red[0];
}

__global__ __launch_bounds__(256) void scan_part2(int* __restrict__ bsum) {
    __shared__ int sh[256];
    int t = threadIdx.x;
    int v = (t < NB_SCAN) ? bsum[t] : 0;
    sh[t] = v;
    __syncthreads();
    for (int off = 1; off < 256; off <<= 1) {
        int u = (t >= off) ? sh[t - off] : 0;
        __syncthreads();
        sh[t] += u;
        __syncthreads();
    }
    if (t < NB_SCAN) bsum[t] = sh[t] - v;   // exclusive
}

__global__ __launch_bounds__(256) void scan_part3(const int* __restrict__ cnt,
                                                  const int* __restrict__ bsum,
                                                  int* __restrict__ ptrb,
                                                  float* __restrict__ dinv) {
    __shared__ int sh[256];
    int t = threadIdx.x;
    int i = blockIdx.x * 256 + t;
    int v = (i < N_NODES) ? cnt[i] : 0;
    sh[t] = v;
    __syncthreads();
    for (int off = 1; off < 256; off <<= 1) {
        int u = (t >= off) ? sh[t - off] : 0;
        __syncthreads();
        sh[t] += u;
        __syncthreads();
    }
    int excl = sh[t] - v + bsum[blockIdx.x];
    if (i < N_NODES) {
        ptrb[i] = excl;
        dinv[i] = rsqrtf((float)v);   // deg >= 1 (self loop)
    }
    if (i == N_NODES - 1) ptrb[N_NODES] = excl + v;
}

__global__ __launch_bounds__(256) void bucket(const int* __restrict__ erow,
                                              const int* __restrict__ ecol,
                                              const int* __restrict__ aux,
                                              const int* __restrict__ ptrb,
                                              const float* __restrict__ dinv,
                                              int2* __restrict__ epack) {
    int e = blockIdx.x * 256 + threadIdx.x;
    if (e >= ET) return;
    int r, c;
    if (e < E_EDGES) { r = erow[e]; c = ecol[e]; }
    else             { r = e - E_EDGES; c = r; }
    int pos = ptrb[c] + aux[e];
    epack[pos] = make_int2(r, __float_as_int(dinv[r] * dinv[c]));
}

// ---------------- W pre-layout: hi/lo bf16 in B-fragment lane order ----------------

__global__ __launch_bounds__(256) void prep_w(const float* __restrict__ gcn_W,
                                              const float* __restrict__ w1W,
                                              const float* __restrict__ w2W,
                                              unsigned short* __restrict__ gf_hi,
                                              unsigned short* __restrict__ gf_lo,
                                              unsigned short* __restrict__ nf_hi,
                                              unsigned short* __restrict__ nf_lo) {
    int idx = blockIdx.x * 256 + threadIdx.x;
    if (idx < 8192) {                       // gcn: 4 layer x 4 s x 8 nt x 64 lane
        int lane = idx & 63, nt = (idx >> 6) & 7, s = (idx >> 9) & 3, layer = idx >> 11;
        int q = lane >> 4, n = lane & 15;
        const float* W = gcn_W + (size_t)layer * 128 * 128;
        size_t o = (size_t)idx * 8;
#pragma unroll
        for (int j = 0; j < 8; ++j) {
            float x = W[(size_t)(s * 32 + q * 8 + j) * 128 + nt * 16 + n];
            unsigned short h, lo;
            split_hl(x, h, lo);
            gf_hi[o + j] = h; gf_lo[o + j] = lo;
        }
    } else if (idx < 8192 + 4096) {         // gna: 4 layer x 2 s x 8 nt x 64 lane
        int t = idx - 8192;
        int lane = t & 63, nt = (t >> 6) & 7, s = (t >> 9) & 1, layer = t >> 10;
        int q = lane >> 4, n = lane & 15;
        int col = nt * 16 + n;              // <64 -> w1, >=64 -> w2
        const float* W = (col < 64) ? (w1W + (size_t)layer * 64 * 64)
                                    : (w2W + (size_t)layer * 64 * 64);
        int c = col & 63;
        size_t o = (size_t)t * 8;
#pragma unroll
        for (int j = 0; j < 8; ++j) {
            float x = W[(size_t)(s * 32 + q * 8 + j) * 64 + c];
            unsigned short h, lo;
            split_hl(x, h, lo);
            nf_hi[o + j] = h; nf_lo[o + j] = lo;
        }
    }
}

// ---------------- MFMA GEMM, LDS-free (bf16 hi/lo split) -------------------------

__global__ __launch_bounds__(256) void gemm_mfma(
    const float* __restrict__ A, int Kfull,
    const unsigned short* __restrict__ wf_hi, const unsigned short* __restrict__ wf_lo,
    const float* __restrict__ b1, const float* __restrict__ b2,
    const float* __restrict__ avec,
    float* __restrict__ O1, float* __restrict__ O2, float* __restrict__ ta,
    int mode) {
    int tid = threadIdx.x;
    int w  = tid >> 6;
    int l  = tid & 63;
    int lq = l >> 4;
    int ln = l & 15;
    int m0 = blockIdx.x * 64;
    int arow = m0 + w * 16 + ln;
    bool avalid = arow < N_NODES;
    const int nsteps = Kfull >> 5;

    f32x4 acc[8];
#pragma unroll
    for (int i = 0; i < 8; ++i) acc[i] = (f32x4){0.f, 0.f, 0.f, 0.f};

    for (int s = 0; s < nsteps; ++s) {
        float4 a0 = make_float4(0.f, 0.f, 0.f, 0.f);
        float4 a1 = make_float4(0.f, 0.f, 0.f, 0.f);
        if (avalid) {
            const float* ap = A + (size_t)arow * Kfull + s * 32 + lq * 8;
            a0 = *(const float4*)ap;
            a1 = *(const float4*)(ap + 4);
        }
        float xs[8] = {a0.x, a0.y, a0.z, a0.w, a1.x, a1.y, a1.z, a1.w};
        short8 ah, al;
#pragma unroll
        for (int c = 0; c < 8; ++c) {
            unsigned short h, lo;
            split_hl(xs[c], h, lo);
            ah[c] = (short)h; al[c] = (short)lo;
        }
#pragma unroll
        for (int nt = 0; nt < 8; ++nt) {
            size_t fo = ((size_t)(s * 8 + nt) * 64 + l) * 8;
            short8 wh = *(const short8*)(wf_hi + fo);
            short8 wl = *(const short8*)(wf_lo + fo);
            acc[nt] = __builtin_amdgcn_mfma_f32_16x16x32_bf16(ah, wh, acc[nt], 0, 0, 0);
            acc[nt] = __builtin_amdgcn_mfma_f32_16x16x32_bf16(ah, wl, acc[nt], 0, 0, 0);
            acc[nt] = __builtin_amdgcn_mfma_f32_16x16x32_bf16(al, wh, acc[nt], 0, 0, 0);
        }
    }

    if (mode == 0) {
#pragma unroll
        for (int nt = 0; nt < 8; ++nt) {
            int col = nt * 16 + ln;
#pragma unroll
            for (int r = 0; r < 4; ++r) {
                int row = m0 + w * 16 + lq * 4 + r;
                if (row < N_NODES) O1[(size_t)row * 128 + col] = acc[nt][r];
            }
        }
    } else {
        float pa[4] = {0.f, 0.f, 0.f, 0.f};
#pragma unroll
        for (int nt = 0; nt < 4; ++nt) {
            int col = nt * 16 + ln;
            float bb = b1[col];
#pragma unroll
            for (int r = 0; r < 4; ++r) {
                int row = m0 + w * 16 + lq * 4 + r;
                if (row < N_NODES) O1[(size_t)row * 64 + col] = acc[nt][r] + bb;
            }
        }
#pragma unroll
        for (int nt = 4; nt < 8; ++nt) {
            int col = (nt - 4) * 16 + ln;
            float bb = b2[col];
            float av = avec[col];
#pragma unroll
            for (int r = 0; r < 4; ++r) {
                float t2 = acc[nt][r] + bb;
                int row = m0 + w * 16 + lq * 4 + r;
                if (row < N_NODES) O2[(size_t)row * 64 + col] = t2;
                pa[r] += t2 * av;
            }
        }
#pragma unroll
        for (int r = 0; r < 4; ++r) {
            pa[r] += __shfl_xor(pa[r], 1);
            pa[r] += __shfl_xor(pa[r], 2);
            pa[r] += __shfl_xor(pa[r], 4);
            pa[r] += __shfl_xor(pa[r], 8);
            int row = m0 + w * 16 + lq * 4 + r;
            if (ln == 0 && row < N_NODES) ta[row] = pa[r];
        }
    }
}

// ---------------- XCD-sliced edge aggregation ----------------
// Exploits blockIdx%8 -> XCD round-robin (perf heuristic only; correctness
// independent). Each wave aggregates a 32-feature slice (=one 128B line of
// the src row) for one dst. Slice s pinned to XCD pair {2s,2s+1} so each XCD
// only fills 128B per distinct src row instead of 512B.
// Wave layout: sub = lane>>3 (8 edge slots), fl = lane&7 (8 float4 groups).

__global__ __launch_bounds__(256) void agg128_x(const float* __restrict__ h2,
                                                const int* __restrict__ ptrb,
                                                const int2* __restrict__ epack,
                                                const float* __restrict__ bias,
                                                float* __restrict__ out,
                                                int apply_gelu) {
    int b     = blockIdx.x;                  // 50000 blocks
    int slice = (b & 7) >> 1;                // 0..3, XCD-affine
    int chunk = (b >> 3) * 2 + (b & 1);      // 0..12499 within slice
    int dst   = chunk * 4 + (threadIdx.x >> 6);
    int lane  = threadIdx.x & 63;
    if (dst >= N_NODES) return;
    int sub = lane >> 3;
    int fl  = lane & 7;
    int fo  = slice * 32 + fl * 4;           // feature offset
    int p0 = ptrb[dst], p1 = ptrb[dst + 1];
    float4 acc0 = make_float4(0.f, 0.f, 0.f, 0.f);
    float4 acc1 = make_float4(0.f, 0.f, 0.f, 0.f);
    for (int p = p0; p < p1; p += 64) {
        int nb = min(64, p1 - p);            // wave-uniform
        int2 ed = (lane < nb) ? epack[p + lane] : make_int2(0, 0);
        int   srcs = ed.x;
        float nrm  = __int_as_float(ed.y);
        for (int eb = 0; eb < nb; eb += 16) { // uniform trip count
            int e0 = eb + sub;               // sub in 0..7
            int e1 = e0 + 8;
            int c0 = min(e0, nb - 1);
            int c1 = min(e1, nb - 1);
            int   s0  = __shfl(srcs, c0);
            int   s1  = __shfl(srcs, c1);
            float n0r = __shfl(nrm, c0);
            float n1r = __shfl(nrm, c1);
            float n0 = (e0 < nb) ? n0r : 0.f;
            float n1 = (e1 < nb) ? n1r : 0.f;
            float4 v0 = *(const float4*)(h2 + (size_t)s0 * 128 + fo);
            float4 v1 = *(const float4*)(h2 + (size_t)s1 * 128 + fo);
            acc0.x += n0 * v0.x; acc0.y += n0 * v0.y;
            acc0.z += n0 * v0.z; acc0.w += n0 * v0.w;
            acc1.x += n1 * v1.x; acc1.y += n1 * v1.y;
            acc1.z += n1 * v1.z; acc1.w += n1 * v1.w;
        }
    }
    acc0.x += acc1.x; acc0.y += acc1.y; acc0.z += acc1.z; acc0.w += acc1.w;
#pragma unroll
    for (int off = 8; off <= 32; off <<= 1) {   // reduce over the 8 subs
        acc0.x += __shfl_xor(acc0.x, off);
        acc0.y += __shfl_xor(acc0.y, off);
        acc0.z += __shfl_xor(acc0.z, off);
        acc0.w += __shfl_xor(acc0.w, off);
    }
    if (sub == 0) {
        float4 b4 = *(const float4*)(bias + fo);
        float v0 = acc0.x + b4.x, v1 = acc0.y + b4.y;
        float v2 = acc0.z + b4.z, v3 = acc0.w + b4.w;
        if (apply_gelu) {
            v0 = gelu_f(v0); v1 = gelu_f(v1); v2 = gelu_f(v2); v3 = gelu_f(v3);
        }
        *(float4*)(out + (size_t)dst * 128 + fo) = make_float4(v0, v1, v2, v3);
    }
}

// Sliced GNA aggregation: 2 slices x 32 feats; slice pinned to an XCD quad.
// Softmax denominator (feature-independent) recomputed per slice - cheap.
__global__ __launch_bounds__(256) void gna_agg_x(const float* __restrict__ t,
                                                 const float* __restrict__ ta,
                                                 const int* __restrict__ ptrb,
                                                 const int2* __restrict__ epack,
                                                 const float* __restrict__ base,
                                                 float* __restrict__ gout) {
    int b     = blockIdx.x;                  // 25000 blocks
    int slice = (b & 7) >> 2;                // 0..1, XCD-affine
    int chunk = (b >> 3) * 4 + (b & 3);      // 0..12499
    int dst   = chunk * 4 + (threadIdx.x >> 6);
    int lane  = threadIdx.x & 63;
    if (dst >= N_NODES) return;
    int sub = lane >> 3;
    int fl  = lane & 7;
    int fo  = slice * 32 + fl * 4;
    int p0 = ptrb[dst], p1 = ptrb[dst + 1];
    float tac = ta[dst];
    float se = 0.f;
    float4 m0 = make_float4(0.f, 0.f, 0.f, 0.f);
    float4 m1 = make_float4(0.f, 0.f, 0.f, 0.f);
    for (int p = p0; p < p1; p += 64) {
        int nb = min(64, p1 - p);            // wave-uniform
        int2 ed = (lane < nb) ? epack[p + lane] : make_int2(0, 0);
        int srcs = ed.x;
        float tav = (lane < nb) ? ta[srcs] : tac;
        float ev  = expf(tac - tav);
        if (lane < nb) se += ev;
        for (int eb = 0; eb < nb; eb += 16) {
            int e0 = eb + sub;
            int e1 = e0 + 8;
            int c0 = min(e0, nb - 1);
            int c1 = min(e1, nb - 1);
            int   s0  = __shfl(srcs, c0);
            int   s1  = __shfl(srcs, c1);
            float w0r = __shfl(ev, c0);
            float w1r = __shfl(ev, c1);
            float w0 = (e0 < nb) ? w0r : 0.f;
            float w1 = (e1 < nb) ? w1r : 0.f;
            float4 v0 = *(const float4*)(t + (size_t)s0 * 64 + fo);
            float4 v1 = *(const float4*)(t + (size_t)s1 * 64 + fo);
            m0.x += w0 * v0.x; m0.y += w0 * v0.y;
            m0.z += w0 * v0.z; m0.w += w0 * v0.w;
            m1.x += w1 * v1.x; m1.y += w1 * v1.y;
            m1.z += w1 * v1.z; m1.w += w1 * v1.w;
        }
    }
#pragma unroll
    for (int off = 1; off < 64; off <<= 1) se += __shfl_xor(se, off);
    m0.x += m1.x; m0.y += m1.y; m0.z += m1.z; m0.w += m1.w;
#pragma unroll
    for (int off = 8; off <= 32; off <<= 1) {
        m0.x += __shfl_xor(m0.x, off);
        m0.y += __shfl_xor(m0.y, off);
        m0.z += __shfl_xor(m0.z, off);
        m0.w += __shfl_xor(m0.w, off);
    }
    if (sub == 0) {
        float winv = 1.0f / (se + 1e-16f);
        float4 bs = *(const float4*)(base + (size_t)dst * 64 + fo);
        float v0 = bs.x + m0.x * winv;
        float v1 = bs.y + m0.y * winv;
        float v2 = bs.z + m0.z * winv;
        float v3 = bs.w + m0.w * winv;
        *(float4*)(gout + (size_t)dst * 64 + fo) =
            make_float4(gelu_f(v0), gelu_f(v1), gelu_f(v2), gelu_f(v3));
    }
}

// ---------------- launch ----------------

extern "C" void kernel_launch(void* const* d_in, const int* in_sizes, int n_in,
                              void* d_out, int out_size, void* d_ws, size_t ws_size,
                              hipStream_t stream) {
    const float* x     = (const float*)d_in[0];
    const float* s     = (const float*)d_in[1];
    const int*   ei    = (const int*)d_in[2];
    const float* gcn_W = (const float*)d_in[3];
    const float* gcn_b = (const float*)d_in[4];
    const float* w1W   = (const float*)d_in[5];
    const float* w1b   = (const float*)d_in[6];
    const float* w2W   = (const float*)d_in[7];
    const float* w2b   = (const float*)d_in[8];
    const float* ga    = (const float*)d_in[9];

    float* h_out = (float*)d_out;                               // N x 128
    float* g_out = (float*)d_out + (size_t)N_NODES * 128;       // N x 64

    size_t off = 0;
    char* wsb = (char*)d_ws;
    auto take = [&](size_t bytes) {
        void* p = wsb + off;
        off = (off + bytes + 255) & ~(size_t)255;
        return p;
    };
    int*   cnt     = (int*)take((size_t)N_NODES * 4);
    int*   ptrb    = (int*)take((size_t)(N_NODES + 1) * 4);
    int*   aux     = (int*)take((size_t)ET * 4);
    float* dinv    = (float*)take((size_t)N_NODES * 4);
    int2*  epack   = (int2*)take((size_t)ET * 8);
    float* h2      = (float*)take((size_t)N_NODES * 128 * 4);
    float* tbuf    = (float*)take((size_t)N_NODES * 64 * 4);
    float* basebuf = (float*)take((size_t)N_NODES * 64 * 4);
    float* tabuf   = (float*)take((size_t)N_NODES * 4);
    int*   bsum    = (int*)take((size_t)NB_SCAN * 4);
    unsigned short* gf_hi = (unsigned short*)take((size_t)8192 * 8 * 2);
    unsigned short* gf_lo = (unsigned short*)take((size_t)8192 * 8 * 2);
    unsigned short* nf_hi = (unsigned short*)take((size_t)4096 * 8 * 2);
    unsigned short* nf_lo = (unsigned short*)take((size_t)4096 * 8 * 2);
    (void)ws_size; (void)in_sizes; (void)n_in; (void)out_size;

    const int* erow = ei;
    const int* ecol = ei + E_EDGES;

    hipMemsetAsync(cnt, 0, (size_t)N_NODES * 4, stream);

    int ge = (ET + 255) / 256;
    count_pos<<<ge, 256, 0, stream>>>(ecol, cnt, aux);
    scan_part1<<<NB_SCAN, 256, 0, stream>>>(cnt, bsum);
    scan_part2<<<1, 256, 0, stream>>>(bsum);
    scan_part3<<<NB_SCAN, 256, 0, stream>>>(cnt, bsum, ptrb, dinv);
    bucket<<<ge, 256, 0, stream>>>(erow, ecol, aux, ptrb, dinv, epack);
    prep_w<<<48, 256, 0, stream>>>(gcn_W, w1W, w2W, gf_hi, gf_lo, nf_hi, nf_lo);

    const int mf_blocks = (N_NODES + 63) / 64;           // 782

    // ---- GCN ----
    const float* hin = x;
    for (int l = 0; l < L_LAYERS; ++l) {
        gemm_mfma<<<mf_blocks, 256, 0, stream>>>(
            hin, 128,
            gf_hi + (size_t)l * 4 * 8 * 64 * 8, gf_lo + (size_t)l * 4 * 8 * 64 * 8,
            nullptr, nullptr, nullptr,
            h2, nullptr, nullptr, 0);
        agg128_x<<<50000, 256, 0, stream>>>(h2, ptrb, epack,
                                            gcn_b + (size_t)l * 128, h_out,
                                            (l < L_LAYERS - 1) ? 1 : 0);
        hin = h_out;
    }

    // ---- GNA ----
    const float* gin = s;
    for (int l = 0; l < L_LAYERS; ++l) {
        gemm_mfma<<<mf_blocks, 256, 0, stream>>>(
            gin, 64,
            nf_hi + (size_t)l * 2 * 8 * 64 * 8, nf_lo + (size_t)l * 2 * 8 * 64 * 8,
            w1b + (size_t)l * 64, w2b + (size_t)l * 64, ga + (size_t)l * 64,
            basebuf, tbuf, tabuf, 1);
        gna_agg_x<<<25000, 256, 0, stream>>>(tbuf, tabuf, ptrb, epack, basebuf, g_out);
        gin = g_out;
    }
}